// Round 4
// baseline (293.077 us; speedup 1.0000x reference)
//
#include <hip/hip_runtime.h>

// Problem dims
#define B_SZ 32
#define L_SZ 256
#define D_SZ 512
#define F_SZ 2048
#define E_SZ 8
#define P_SZ 64   // B_SZ * TOP_K
#define BK   64   // K-chunk staged per LDS tile (2 MFMA substeps of 32)

typedef __attribute__((ext_vector_type(8))) short bf16x8;
typedef __attribute__((ext_vector_type(4))) float f32x4;

// f32 -> bf16 round-to-nearest-even (finite inputs only)
__device__ __forceinline__ unsigned short f2bf(float f) {
  unsigned int u = __builtin_bit_cast(unsigned int, f);
  u += 0x7fffu + ((u >> 16) & 1u);
  return (unsigned short)(u >> 16);
}

// async global->LDS, 16B per lane; LDS dest is wave-uniform base + lane*16
__device__ __forceinline__ void async16(const void* g, void* l) {
  __builtin_amdgcn_global_load_lds(
      (const __attribute__((address_space(1))) unsigned int*)g,
      (__attribute__((address_space(3))) unsigned int*)l, 16, 0, 0);
}

// exact gelu via A&S 7.1.26 erf (max abs err ~1.5e-7), fast hw exp/rcp
__device__ __forceinline__ float gelu_f(float x) {
  float a = fabsf(x) * 0.70710678118654752f;
  float t = __builtin_amdgcn_rcpf(1.0f + 0.3275911f * a);
  float y = t * (0.254829592f +
            t * (-0.284496736f +
            t * (1.421413741f +
            t * (-1.453152027f +
            t * 1.061405429f))));
  float e = __expf(-a * a);
  float erf_abs = 1.0f - y * e;
  float erf_v = (x < 0.f) ? -erf_abs : erf_abs;
  return 0.5f * x * (1.0f + erf_v);
}

// ------------- fused prep: gates | x->bf16 | W1^T->bf16 | W2^T->bf16 ----
#define PREP_CONV_BLKS 4096
#define PREP_TR_BLKS   2048
#define PREP_TOTAL     (1 + PREP_CONV_BLKS + 2 * PREP_TR_BLKS)

__global__ __launch_bounds__(256) void prep_kernel(
    const float* __restrict__ logits, const int* __restrict__ masks,
    const float* __restrict__ x,
    const float* __restrict__ W1, const float* __restrict__ W2,
    int* __restrict__ sel_e, float* __restrict__ sel_g,
    unsigned short* __restrict__ xb,
    unsigned short* __restrict__ w1t, unsigned short* __restrict__ w2t) {
  __shared__ float tile[64][65];
  int blk = blockIdx.x;
  int tid = threadIdx.x;

  if (blk == 0) {
    int b = tid;
    if (b >= B_SZ) return;
    float lg[E_SZ], p[E_SZ];
    float mx = -1e30f;
    for (int e = 0; e < E_SZ; ++e) { lg[e] = logits[b * E_SZ + e]; mx = fmaxf(mx, lg[e]); }
    float s = 0.f;
    for (int e = 0; e < E_SZ; ++e) { p[e] = expf(lg[e] - mx); s += p[e]; }
    for (int e = 0; e < E_SZ; ++e) p[e] = (masks[b * E_SZ + e] == 1) ? (p[e] / s) : 0.f;
    int i0 = 0, i1 = 1; float v0 = -1.f, v1 = -1.f;
    for (int e = 0; e < E_SZ; ++e) {
      float v = p[e];
      if (v > v0)      { v1 = v0; i1 = i0; v0 = v; i0 = e; }
      else if (v > v1) { v1 = v;  i1 = e; }
    }
    float den = v0 + v1 + 1e-9f;
    sel_e[2 * b] = i0;  sel_e[2 * b + 1] = i1;
    sel_g[2 * b] = v0 / den;
    sel_g[2 * b + 1] = v1 / den;
    return;
  }
  blk -= 1;

  if (blk < PREP_CONV_BLKS) {
    int i = blk * 256 + tid;
    float4 v = ((const float4*)x)[i];
    ushort4 o;
    o.x = f2bf(v.x); o.y = f2bf(v.y); o.z = f2bf(v.z); o.w = f2bf(v.w);
    ((ushort4*)xb)[i] = o;
    return;
  }
  blk -= PREP_CONV_BLKS;

  const float* in; unsigned short* out; int R, C, ls;
  if (blk < PREP_TR_BLKS) { in = W1; out = w1t; R = D_SZ; C = F_SZ; ls = 5; }
  else { blk -= PREP_TR_BLKS; in = W2; out = w2t; R = F_SZ; C = D_SZ; ls = 3; }
  int z = blk >> 8;
  int rem = blk & 255;
  int tr = rem >> ls, tc = rem & ((1 << ls) - 1);
  int r0 = tr * 64, c0 = tc * 64;
  const float* ip = in + (size_t)z * R * C;
  unsigned short* op = out + (size_t)z * C * R;
  int tx = tid & 63, ty = tid >> 6;
#pragma unroll
  for (int i = 0; i < 16; ++i) {
    int r = i * 4 + ty;
    tile[r][tx] = ip[(size_t)(r0 + r) * C + c0 + tx];
  }
  __syncthreads();
#pragma unroll
  for (int uu = 0; uu < 4; ++uu) {
    int u = uu * 256 + tid;
    int cc = u >> 4, q = u & 15;
    ushort4 o;
    o.x = f2bf(tile[q * 4 + 0][cc]);
    o.y = f2bf(tile[q * 4 + 1][cc]);
    o.z = f2bf(tile[q * 4 + 2][cc]);
    o.w = f2bf(tile[q * 4 + 3][cc]);
    *(ushort4*)(op + (size_t)(c0 + cc) * R + r0 + q * 4) = o;
  }
}

// ------------- stage 1: H[p] = gelu(X_b @ W1[e] + b1[e]) ---------------
// A (x-tile) direct from global (L1/L2-resident); B (W1t) via LDS BK=64.
// 1-D grid 2048, swizzled: 16 f-blocks sharing one A-tile pinned to one XCD.
__global__ __launch_bounds__(256, 3) void moe_gemm1(
    const unsigned short* __restrict__ Xb,
    const unsigned short* __restrict__ W1t,
    const float* __restrict__ b1,
    const int* __restrict__ sel_e,
    unsigned short* __restrict__ H) {
  __shared__ __align__(16) char smem[33792];
  unsigned short* Bs = (unsigned short*)smem;      // [128][BK] row-major, packed

  int lin = blockIdx.x;
  int xcd = lin & 7;
  int f   = (lin >> 3) & 15;
  int grp = lin >> 7;
  int pl  = grp * 8 + xcd;       // 0..127
  int p   = pl >> 1;
  int l0  = (pl & 1) * 128;
  int f0  = f * 128;
  int b   = p >> 1;
  int e   = sel_e[p];

  int tid = threadIdx.x;
  int lane = tid & 63;
  int w = tid >> 6, wm = w & 1, wn = w >> 1;
  int lrow = lane & 15, kg = lane >> 4;

  const unsigned short* Bbase = W1t + ((size_t)e * F_SZ + f0) * D_SZ;
  // A row pointers (lane's MFMA rows)
  const unsigned short* Arow[4];
#pragma unroll
  for (int i = 0; i < 4; ++i)
    Arow[i] = Xb + ((size_t)b * L_SZ + l0 + wm * 64 + i * 16 + lrow) * D_SZ + kg * 8;

  // staging: 1024 segs of 16B; call c: seg = c*256 + tid
  int srow[4], skof[4];
#pragma unroll
  for (int c = 0; c < 4; ++c) {
    int seg = c * 256 + tid;
    srow[c] = seg >> 3;
    skof[c] = (seg & 7) * 8;
  }

  f32x4 acc[4][4] = {};

  for (int k0 = 0; k0 < D_SZ; k0 += BK) {
#pragma unroll
    for (int c = 0; c < 4; ++c)
      async16(Bbase + (size_t)srow[c] * D_SZ + k0 + skof[c],
              Bs + (size_t)(c * 256 + tid) * 8);
    // A frags for both substeps (in flight during B-DMA drain)
    bf16x8 a[2][4];
#pragma unroll
    for (int s = 0; s < 2; ++s)
#pragma unroll
      for (int i = 0; i < 4; ++i)
        a[s][i] = *(const bf16x8*)(Arow[i] + k0 + s * 32);
    __syncthreads();
#pragma unroll
    for (int s = 0; s < 2; ++s) {
      bf16x8 bf[4];
#pragma unroll
      for (int j = 0; j < 4; ++j)
        bf[j] = *(const bf16x8*)&Bs[(wn * 64 + j * 16 + lrow) * BK + s * 32 + kg * 8];
#pragma unroll
      for (int i = 0; i < 4; ++i)
#pragma unroll
        for (int j = 0; j < 4; ++j)
          acc[i][j] = __builtin_amdgcn_mfma_f32_16x16x32_bf16(a[s][i], bf[j], acc[i][j], 0, 0, 0);
    }
    __syncthreads();
  }

  // epilogue: +b1, gelu, bf16; LDS transpose -> 256B-coalesced 16B stores
  float b1v[4];
#pragma unroll
  for (int j = 0; j < 4; ++j)
    b1v[j] = b1[e * F_SZ + f0 + wn * 64 + j * 16 + lrow];

  unsigned short* Ep = (unsigned short*)smem;      // [128][132] (pad 4)
#pragma unroll
  for (int i = 0; i < 4; ++i) {
    int rbase = wm * 64 + i * 16 + kg * 4;
#pragma unroll
    for (int j = 0; j < 4; ++j) {
      int c = wn * 64 + j * 16 + lrow;
#pragma unroll
      for (int r = 0; r < 4; ++r)
        Ep[(rbase + r) * 132 + c] = f2bf(gelu_f(acc[i][j][r] + b1v[j]));
    }
  }
  __syncthreads();
  unsigned short* Hp = H + ((size_t)p * L_SZ + l0) * F_SZ + f0;
#pragma unroll
  for (int u = 0; u < 8; ++u) {
    int row = u * 16 + (tid >> 4);
    int colb = (tid & 15) * 8;
    bf16x8 v = *(const bf16x8*)&Ep[row * 132 + colb];
    *(bf16x8*)(Hp + (size_t)row * F_SZ + colb) = v;
  }
}

// ------------- stage 2 (slot-split, A=H direct, B=W2t via LDS) ---------
// even slot -> part = g0*acc ; odd slot -> Out = g1*acc + (g0*b2[e0]+g1*b2[e1])
__global__ __launch_bounds__(256, 3) void moe_gemm2(
    const unsigned short* __restrict__ H,
    const unsigned short* __restrict__ W2t,
    const float* __restrict__ b2,
    const int* __restrict__ sel_e,
    const float* __restrict__ sel_g,
    float* __restrict__ part,
    float* __restrict__ Out) {
  __shared__ __align__(16) char smem[33792];
  unsigned short* Bs = (unsigned short*)smem;      // [128][BK]

  int lin = blockIdx.x;
  int xcd = lin & 7;
  int d   = (lin >> 3) & 3;
  int grp = lin >> 5;
  int pl  = grp * 8 + xcd;       // 0..127
  int p   = pl >> 1;
  int l0  = (pl & 1) * 128;
  int d0  = d * 128;
  int b   = p >> 1;
  int e   = sel_e[p];
  float g = sel_g[p];

  int tid = threadIdx.x;
  int lane = tid & 63;
  int w = tid >> 6, wm = w & 1, wn = w >> 1;
  int lrow = lane & 15, kg = lane >> 4;

  const unsigned short* Bbase = W2t + ((size_t)e * D_SZ + d0) * F_SZ;
  const unsigned short* Arow[4];
#pragma unroll
  for (int i = 0; i < 4; ++i)
    Arow[i] = H + ((size_t)p * L_SZ + l0 + wm * 64 + i * 16 + lrow) * F_SZ + kg * 8;

  int srow[4], skof[4];
#pragma unroll
  for (int c = 0; c < 4; ++c) {
    int seg = c * 256 + tid;
    srow[c] = seg >> 3;
    skof[c] = (seg & 7) * 8;
  }

  f32x4 acc[4][4] = {};

  for (int k0 = 0; k0 < F_SZ; k0 += BK) {
#pragma unroll
    for (int c = 0; c < 4; ++c)
      async16(Bbase + (size_t)srow[c] * F_SZ + k0 + skof[c],
              Bs + (size_t)(c * 256 + tid) * 8);
    bf16x8 a[2][4];
#pragma unroll
    for (int s = 0; s < 2; ++s)
#pragma unroll
      for (int i = 0; i < 4; ++i)
        a[s][i] = *(const bf16x8*)(Arow[i] + k0 + s * 32);
    __syncthreads();
#pragma unroll
    for (int s = 0; s < 2; ++s) {
      bf16x8 bf[4];
#pragma unroll
      for (int j = 0; j < 4; ++j)
        bf[j] = *(const bf16x8*)&Bs[(wn * 64 + j * 16 + lrow) * BK + s * 32 + kg * 8];
#pragma unroll
      for (int i = 0; i < 4; ++i)
#pragma unroll
        for (int j = 0; j < 4; ++j)
          acc[i][j] = __builtin_amdgcn_mfma_f32_16x16x32_bf16(a[s][i], bf[j], acc[i][j], 0, 0, 0);
    }
    __syncthreads();
  }

  // epilogue: gate-scale (+ bias on odd slot), LDS f32 transpose in 2 chunks,
  // 512B-coalesced float4 stores
  float bias[4] = {0.f, 0.f, 0.f, 0.f};
  if (p & 1) {
    int e0 = sel_e[2 * b], e1 = sel_e[2 * b + 1];
    float g0 = sel_g[2 * b], g1 = sel_g[2 * b + 1];
#pragma unroll
    for (int j = 0; j < 4; ++j) {
      int dd = d0 + wn * 64 + j * 16 + lrow;
      bias[j] = g0 * b2[e0 * D_SZ + dd] + g1 * b2[e1 * D_SZ + dd];
    }
  }
  float* dst = (p & 1) ? Out : part;
  float* Op = dst + ((size_t)b * L_SZ + l0) * D_SZ + d0;
  float* Ef = (float*)smem;                        // [64][130] (pad 2)
#pragma unroll
  for (int h = 0; h < 2; ++h) {
    __syncthreads();
    if (wm == h) {
#pragma unroll
      for (int i = 0; i < 4; ++i) {
        int rl = i * 16 + kg * 4;
#pragma unroll
        for (int j = 0; j < 4; ++j) {
          int c = wn * 64 + j * 16 + lrow;
#pragma unroll
          for (int r = 0; r < 4; ++r)
            Ef[(rl + r) * 130 + c] = g * acc[i][j][r] + bias[j];
        }
      }
    }
    __syncthreads();
#pragma unroll
    for (int u = 0; u < 8; ++u) {
      int rl = u * 8 + (tid >> 5);
      int c4 = (tid & 31) * 4;
      float4 v = *(const float4*)&Ef[rl * 130 + c4];
      *(float4*)(Op + (size_t)(h * 64 + rl) * D_SZ + c4) = v;
    }
  }
}

// ------------- combine: Out += part ------------------------------------
__global__ __launch_bounds__(256) void combine_kernel(
    const float* __restrict__ part, float* __restrict__ Out) {
  int i = blockIdx.x * 256 + threadIdx.x;
  float4 pv = ((const float4*)part)[i];
  float4 o  = ((float4*)Out)[i];
  o.x += pv.x; o.y += pv.y; o.z += pv.z; o.w += pv.w;
  ((float4*)Out)[i] = o;
}

extern "C" void kernel_launch(void* const* d_in, const int* in_sizes, int n_in,
                              void* d_out, int out_size, void* d_ws, size_t ws_size,
                              hipStream_t stream) {
  const float* x      = (const float*)d_in[0];
  const float* logits = (const float*)d_in[1];
  const int*   masks  = (const int*)d_in[2];
  const float* W1     = (const float*)d_in[3];
  const float* b1     = (const float*)d_in[4];
  const float* W2     = (const float*)d_in[5];
  const float* b2     = (const float*)d_in[6];
  float* out = (float*)d_out;

  // workspace: sel (1K) | xb 8MB | w1t 16MB | w2t 16MB | H 64MB
  // part (16MB f32) aliases [xb .. first half of w1t] — dead after gemm1.
  char* ws = (char*)d_ws;
  int*   sel_e = (int*)ws;
  float* sel_g = (float*)(ws + 256);
  unsigned short* xb  = (unsigned short*)(ws + 1024);
  unsigned short* w1t = xb  + (size_t)B_SZ * L_SZ * D_SZ;
  unsigned short* w2t = w1t + (size_t)E_SZ * F_SZ * D_SZ;
  unsigned short* Hbuf = w2t + (size_t)E_SZ * D_SZ * F_SZ;
  float* part = (float*)(ws + 1024);

  prep_kernel<<<PREP_TOTAL, 256, 0, stream>>>(logits, masks, x, W1, W2,
                                              sel_e, sel_g, xb, w1t, w2t);
  moe_gemm1<<<2048, 256, 0, stream>>>(xb, w1t, b1, sel_e, Hbuf);
  moe_gemm2<<<512, 256, 0, stream>>>(Hbuf, w2t, b2, sel_e, sel_g, part, out);
  combine_kernel<<<(B_SZ * L_SZ * D_SZ / 4) / 256, 256, 0, stream>>>(part, out);
}

// Round 5
// 245.531 us; speedup vs baseline: 1.1936x; 1.1936x over previous
//
#include <hip/hip_runtime.h>

// Problem dims
#define B_SZ 32
#define L_SZ 256
#define D_SZ 512
#define F_SZ 2048
#define E_SZ 8
#define P_SZ 64   // B_SZ * TOP_K
#define BK2  32   // LDS sub-tile K width (two sub-tiles per barrier-pair -> K=64)

typedef __attribute__((ext_vector_type(8)))  short bf16x8;
typedef __attribute__((ext_vector_type(16))) float f32x16;

// f32 -> bf16 round-to-nearest-even (finite inputs only)
__device__ __forceinline__ unsigned short f2bf(float f) {
  unsigned int u = __builtin_bit_cast(unsigned int, f);
  u += 0x7fffu + ((u >> 16) & 1u);
  return (unsigned short)(u >> 16);
}

// async global->LDS, 16B per lane; LDS dest is wave-uniform base + lane*16
__device__ __forceinline__ void async16(const void* g, void* l) {
  __builtin_amdgcn_global_load_lds(
      (const __attribute__((address_space(1))) unsigned int*)g,
      (__attribute__((address_space(3))) unsigned int*)l, 16, 0, 0);
}

// exact gelu via A&S 7.1.26 erf (max abs err ~1.5e-7), fast hw exp/rcp
__device__ __forceinline__ float gelu_f(float x) {
  float a = fabsf(x) * 0.70710678118654752f;
  float t = __builtin_amdgcn_rcpf(1.0f + 0.3275911f * a);
  float y = t * (0.254829592f +
            t * (-0.284496736f +
            t * (1.421413741f +
            t * (-1.453152027f +
            t * 1.061405429f))));
  float e = __expf(-a * a);
  float erf_abs = 1.0f - y * e;
  float erf_v = (x < 0.f) ? -erf_abs : erf_abs;
  return 0.5f * x * (1.0f + erf_v);
}

// ------------- fused prep: gates | x->bf16 | W1^T->bf16 | W2^T->bf16 ----
#define PREP_CONV_BLKS 4096
#define PREP_TR_BLKS   2048
#define PREP_TOTAL     (1 + PREP_CONV_BLKS + 2 * PREP_TR_BLKS)

__global__ __launch_bounds__(256) void prep_kernel(
    const float* __restrict__ logits, const int* __restrict__ masks,
    const float* __restrict__ x,
    const float* __restrict__ W1, const float* __restrict__ W2,
    int* __restrict__ sel_e, float* __restrict__ sel_g,
    unsigned short* __restrict__ xb,
    unsigned short* __restrict__ w1t, unsigned short* __restrict__ w2t) {
  __shared__ float tile[64][65];
  int blk = blockIdx.x;
  int tid = threadIdx.x;

  if (blk == 0) {
    int b = tid;
    if (b >= B_SZ) return;
    float lg[E_SZ], p[E_SZ];
    float mx = -1e30f;
    for (int e = 0; e < E_SZ; ++e) { lg[e] = logits[b * E_SZ + e]; mx = fmaxf(mx, lg[e]); }
    float s = 0.f;
    for (int e = 0; e < E_SZ; ++e) { p[e] = expf(lg[e] - mx); s += p[e]; }
    for (int e = 0; e < E_SZ; ++e) p[e] = (masks[b * E_SZ + e] == 1) ? (p[e] / s) : 0.f;
    int i0 = 0, i1 = 1; float v0 = -1.f, v1 = -1.f;
    for (int e = 0; e < E_SZ; ++e) {
      float v = p[e];
      if (v > v0)      { v1 = v0; i1 = i0; v0 = v; i0 = e; }
      else if (v > v1) { v1 = v;  i1 = e; }
    }
    float den = v0 + v1 + 1e-9f;
    sel_e[2 * b] = i0;  sel_e[2 * b + 1] = i1;
    sel_g[2 * b] = v0 / den;
    sel_g[2 * b + 1] = v1 / den;
    return;
  }
  blk -= 1;

  if (blk < PREP_CONV_BLKS) {
    int i = blk * 256 + tid;
    float4 v = ((const float4*)x)[i];
    ushort4 o;
    o.x = f2bf(v.x); o.y = f2bf(v.y); o.z = f2bf(v.z); o.w = f2bf(v.w);
    ((ushort4*)xb)[i] = o;
    return;
  }
  blk -= PREP_CONV_BLKS;

  const float* in; unsigned short* out; int R, C, ls;
  if (blk < PREP_TR_BLKS) { in = W1; out = w1t; R = D_SZ; C = F_SZ; ls = 5; }
  else { blk -= PREP_TR_BLKS; in = W2; out = w2t; R = F_SZ; C = D_SZ; ls = 3; }
  int z = blk >> 8;
  int rem = blk & 255;
  int tr = rem >> ls, tc = rem & ((1 << ls) - 1);
  int r0 = tr * 64, c0 = tc * 64;
  const float* ip = in + (size_t)z * R * C;
  unsigned short* op = out + (size_t)z * C * R;
  int tx = tid & 63, ty = tid >> 6;
#pragma unroll
  for (int i = 0; i < 16; ++i) {
    int r = i * 4 + ty;
    tile[r][tx] = ip[(size_t)(r0 + r) * C + c0 + tx];
  }
  __syncthreads();
#pragma unroll
  for (int uu = 0; uu < 4; ++uu) {
    int u = uu * 256 + tid;
    int cc = u >> 4, q = u & 15;
    ushort4 o;
    o.x = f2bf(tile[q * 4 + 0][cc]);
    o.y = f2bf(tile[q * 4 + 1][cc]);
    o.z = f2bf(tile[q * 4 + 2][cc]);
    o.w = f2bf(tile[q * 4 + 3][cc]);
    *(ushort4*)(op + (size_t)(c0 + cc) * R + r0 + q * 4) = o;
  }
}

// ------------- stage 1: H[p] = gelu(X_b @ W1[e] + b1[e]) ---------------
// Both operands staged via global_load_lds (two BK=32 sub-tiles per barrier).
// 32x32x16 MFMA; wave tile 64x64 = 2x2 of 32x32.
// 1-D grid 2048, swizzled: the 16 f-blocks sharing an x-tile pin to one XCD.
__global__ __launch_bounds__(256, 4) void moe_gemm1(
    const unsigned short* __restrict__ Xb,
    const unsigned short* __restrict__ W1t,
    const float* __restrict__ b1,
    const int* __restrict__ sel_e,
    unsigned short* __restrict__ H) {
  __shared__ __align__(16) unsigned short As[2][128 * BK2];
  __shared__ __align__(16) unsigned short Bs[2][128 * BK2];

  int lin = blockIdx.x;
  int xcd = lin & 7;
  int f   = (lin >> 3) & 15;
  int grp = lin >> 7;
  int pl  = grp * 8 + xcd;       // 0..127
  int p   = pl >> 1;
  int l0  = (pl & 1) * 128;
  int f0  = f * 128;
  int b   = p >> 1;
  int e   = sel_e[p];

  int tid = threadIdx.x;
  int lane = tid & 63;
  int w = tid >> 6, wm = w & 1, wn = w >> 1;
  int m32 = lane & 31, kh = lane >> 5;

  const unsigned short* Abase = Xb  + ((size_t)b * L_SZ + l0) * D_SZ;
  const unsigned short* Bbase = W1t + ((size_t)e * F_SZ + f0) * D_SZ;

  // staging: 512 segs of 16B per sub-tile; thread does seg0 = w*128+lane, +64
  int seg0 = w * 128 + lane;
  int row0 = seg0 >> 2, ks0 = (seg0 & 3) * 8;
  int seg1 = seg0 + 64;
  int row1 = seg1 >> 2, ks1 = (seg1 & 3) * 8;

  f32x16 acc[2][2] = {};

  for (int k0 = 0; k0 < D_SZ; k0 += 2 * BK2) {
#pragma unroll
    for (int h = 0; h < 2; ++h) {
      int kk = k0 + h * BK2;
      async16(Abase + (size_t)row0 * D_SZ + kk + ks0, &As[h][seg0 * 8]);
      async16(Abase + (size_t)row1 * D_SZ + kk + ks1, &As[h][seg1 * 8]);
      async16(Bbase + (size_t)row0 * D_SZ + kk + ks0, &Bs[h][seg0 * 8]);
      async16(Bbase + (size_t)row1 * D_SZ + kk + ks1, &Bs[h][seg1 * 8]);
    }
    __syncthreads();
#pragma unroll
    for (int h = 0; h < 2; ++h)
#pragma unroll
      for (int s = 0; s < 2; ++s) {     // K=16 substep: k' = s*16 + kh*8
        int ko = s * 16 + kh * 8;
        bf16x8 a0 = *(const bf16x8*)&As[h][(wm * 64 +      m32) * BK2 + ko];
        bf16x8 a1 = *(const bf16x8*)&As[h][(wm * 64 + 32 + m32) * BK2 + ko];
        bf16x8 b0 = *(const bf16x8*)&Bs[h][(wn * 64 +      m32) * BK2 + ko];
        bf16x8 b1f = *(const bf16x8*)&Bs[h][(wn * 64 + 32 + m32) * BK2 + ko];
        acc[0][0] = __builtin_amdgcn_mfma_f32_32x32x16_bf16(a0, b0,  acc[0][0], 0, 0, 0);
        acc[0][1] = __builtin_amdgcn_mfma_f32_32x32x16_bf16(a0, b1f, acc[0][1], 0, 0, 0);
        acc[1][0] = __builtin_amdgcn_mfma_f32_32x32x16_bf16(a1, b0,  acc[1][0], 0, 0, 0);
        acc[1][1] = __builtin_amdgcn_mfma_f32_32x32x16_bf16(a1, b1f, acc[1][1], 0, 0, 0);
      }
    __syncthreads();
  }

  // epilogue: +b1, gelu, bf16 direct stores (32 lanes -> 64B contiguous)
  float b1v[2];
#pragma unroll
  for (int tj = 0; tj < 2; ++tj)
    b1v[tj] = b1[e * F_SZ + f0 + wn * 64 + tj * 32 + m32];

  unsigned short* Hp = H + ((size_t)p * L_SZ + l0) * F_SZ + f0;
#pragma unroll
  for (int ti = 0; ti < 2; ++ti)
#pragma unroll
    for (int tj = 0; tj < 2; ++tj) {
      int col = wn * 64 + tj * 32 + m32;
#pragma unroll
      for (int r = 0; r < 16; ++r) {
        int row = wm * 64 + ti * 32 + (r & 3) + 8 * (r >> 2) + 4 * kh;
        Hp[(size_t)row * F_SZ + col] = f2bf(gelu_f(acc[ti][tj][r] + b1v[tj]));
      }
    }
}

// ------------- stage 2 (slot-split, full K, no atomics) ----------------
// even slot p -> part = g0*acc ; odd slot p -> Out = g1*acc + gate-wtd b2
__global__ __launch_bounds__(256, 4) void moe_gemm2(
    const unsigned short* __restrict__ H,
    const unsigned short* __restrict__ W2t,
    const float* __restrict__ b2,
    const int* __restrict__ sel_e,
    const float* __restrict__ sel_g,
    float* __restrict__ part,
    float* __restrict__ Out) {
  __shared__ __align__(16) unsigned short As[2][128 * BK2];
  __shared__ __align__(16) unsigned short Bs[2][128 * BK2];

  int lin = blockIdx.x;
  int q   = lin & 7;
  int d   = (lin >> 3) & 3;
  int g8  = lin >> 5;
  int gg  = g8 * 8 + q;          // (p, l-tile), 0..127 — same XCD across d
  int p   = gg >> 1;
  int l0  = (gg & 1) * 128;
  int d0  = d * 128;
  int b   = p >> 1;
  int e   = sel_e[p];
  float g = sel_g[p];

  int tid = threadIdx.x;
  int lane = tid & 63;
  int w = tid >> 6, wm = w & 1, wn = w >> 1;
  int m32 = lane & 31, kh = lane >> 5;

  const unsigned short* Abase = H   + ((size_t)p * L_SZ + l0) * F_SZ;
  const unsigned short* Bbase = W2t + ((size_t)e * D_SZ + d0) * F_SZ;

  int seg0 = w * 128 + lane;
  int row0 = seg0 >> 2, ks0 = (seg0 & 3) * 8;
  int seg1 = seg0 + 64;
  int row1 = seg1 >> 2, ks1 = (seg1 & 3) * 8;

  f32x16 acc[2][2] = {};

  for (int k0 = 0; k0 < F_SZ; k0 += 2 * BK2) {
#pragma unroll
    for (int h = 0; h < 2; ++h) {
      int kk = k0 + h * BK2;
      async16(Abase + (size_t)row0 * F_SZ + kk + ks0, &As[h][seg0 * 8]);
      async16(Abase + (size_t)row1 * F_SZ + kk + ks1, &As[h][seg1 * 8]);
      async16(Bbase + (size_t)row0 * F_SZ + kk + ks0, &Bs[h][seg0 * 8]);
      async16(Bbase + (size_t)row1 * F_SZ + kk + ks1, &Bs[h][seg1 * 8]);
    }
    __syncthreads();
#pragma unroll
    for (int h = 0; h < 2; ++h)
#pragma unroll
      for (int s = 0; s < 2; ++s) {
        int ko = s * 16 + kh * 8;
        bf16x8 a0 = *(const bf16x8*)&As[h][(wm * 64 +      m32) * BK2 + ko];
        bf16x8 a1 = *(const bf16x8*)&As[h][(wm * 64 + 32 + m32) * BK2 + ko];
        bf16x8 b0 = *(const bf16x8*)&Bs[h][(wn * 64 +      m32) * BK2 + ko];
        bf16x8 b1f = *(const bf16x8*)&Bs[h][(wn * 64 + 32 + m32) * BK2 + ko];
        acc[0][0] = __builtin_amdgcn_mfma_f32_32x32x16_bf16(a0, b0,  acc[0][0], 0, 0, 0);
        acc[0][1] = __builtin_amdgcn_mfma_f32_32x32x16_bf16(a0, b1f, acc[0][1], 0, 0, 0);
        acc[1][0] = __builtin_amdgcn_mfma_f32_32x32x16_bf16(a1, b0,  acc[1][0], 0, 0, 0);
        acc[1][1] = __builtin_amdgcn_mfma_f32_32x32x16_bf16(a1, b1f, acc[1][1], 0, 0, 0);
      }
    __syncthreads();
  }

  // epilogue: gate-scale (+ gate-weighted b2 on odd slot), direct f32 stores
  float bias[2] = {0.f, 0.f};
  if (p & 1) {
    int e0 = sel_e[2 * b], e1 = sel_e[2 * b + 1];
    float g0 = sel_g[2 * b], g1 = sel_g[2 * b + 1];
#pragma unroll
    for (int tj = 0; tj < 2; ++tj) {
      int dd = d0 + wn * 64 + tj * 32 + m32;
      bias[tj] = g0 * b2[e0 * D_SZ + dd] + g1 * b2[e1 * D_SZ + dd];
    }
  }
  float* dst = (p & 1) ? Out : part;
  float* Op = dst + ((size_t)b * L_SZ + l0) * D_SZ + d0;
#pragma unroll
  for (int ti = 0; ti < 2; ++ti)
#pragma unroll
    for (int tj = 0; tj < 2; ++tj) {
      int col = wn * 64 + tj * 32 + m32;
#pragma unroll
      for (int r = 0; r < 16; ++r) {
        int row = wm * 64 + ti * 32 + (r & 3) + 8 * (r >> 2) + 4 * kh;
        Op[(size_t)row * D_SZ + col] = g * acc[ti][tj][r] + bias[tj];
      }
    }
}

// ------------- combine: Out += part ------------------------------------
__global__ __launch_bounds__(256) void combine_kernel(
    const float* __restrict__ part, float* __restrict__ Out) {
  int i = blockIdx.x * 256 + threadIdx.x;
  float4 pv = ((const float4*)part)[i];
  float4 o  = ((float4*)Out)[i];
  o.x += pv.x; o.y += pv.y; o.z += pv.z; o.w += pv.w;
  ((float4*)Out)[i] = o;
}

extern "C" void kernel_launch(void* const* d_in, const int* in_sizes, int n_in,
                              void* d_out, int out_size, void* d_ws, size_t ws_size,
                              hipStream_t stream) {
  const float* x      = (const float*)d_in[0];
  const float* logits = (const float*)d_in[1];
  const int*   masks  = (const int*)d_in[2];
  const float* W1     = (const float*)d_in[3];
  const float* b1     = (const float*)d_in[4];
  const float* W2     = (const float*)d_in[5];
  const float* b2     = (const float*)d_in[6];
  float* out = (float*)d_out;

  // workspace: sel (1K) | xb 8MB | w1t 16MB | w2t 16MB | H 64MB
  // part (16MB f32) aliases [xb .. first half of w1t] — dead after gemm1.
  char* ws = (char*)d_ws;
  int*   sel_e = (int*)ws;
  float* sel_g = (float*)(ws + 256);
  unsigned short* xb  = (unsigned short*)(ws + 1024);
  unsigned short* w1t = xb  + (size_t)B_SZ * L_SZ * D_SZ;
  unsigned short* w2t = w1t + (size_t)E_SZ * F_SZ * D_SZ;
  unsigned short* Hbuf = w2t + (size_t)E_SZ * D_SZ * F_SZ;
  float* part = (float*)(ws + 1024);

  prep_kernel<<<PREP_TOTAL, 256, 0, stream>>>(logits, masks, x, W1, W2,
                                              sel_e, sel_g, xb, w1t, w2t);
  moe_gemm1<<<2048, 256, 0, stream>>>(xb, w1t, b1, sel_e, Hbuf);
  moe_gemm2<<<512, 256, 0, stream>>>(Hbuf, w2t, b2, sel_e, sel_g, part, out);
  combine_kernel<<<(B_SZ * L_SZ * D_SZ / 4) / 256, 256, 0, stream>>>(part, out);
}

// Round 6
// 226.065 us; speedup vs baseline: 1.2964x; 1.0861x over previous
//
#include <hip/hip_runtime.h>

// Problem dims
#define B_SZ 32
#define L_SZ 256
#define D_SZ 512
#define F_SZ 2048
#define E_SZ 8
#define P_SZ 64   // B_SZ * TOP_K
#define BK2  32   // LDS sub-tile K width (two sub-tiles per barrier-pair -> K=64)

typedef __attribute__((ext_vector_type(8)))  short bf16x8;
typedef __attribute__((ext_vector_type(16))) float f32x16;

// f32 -> bf16 round-to-nearest-even (finite inputs only)
__device__ __forceinline__ unsigned short f2bf(float f) {
  unsigned int u = __builtin_bit_cast(unsigned int, f);
  u += 0x7fffu + ((u >> 16) & 1u);
  return (unsigned short)(u >> 16);
}

// async global->LDS, 16B per lane; LDS dest is wave-uniform base + lane*16
__device__ __forceinline__ void async16(const void* g, void* l) {
  __builtin_amdgcn_global_load_lds(
      (const __attribute__((address_space(1))) unsigned int*)g,
      (__attribute__((address_space(3))) unsigned int*)l, 16, 0, 0);
}

// exact gelu via A&S 7.1.26 erf (max abs err ~1.5e-7), fast hw exp/rcp
__device__ __forceinline__ float gelu_f(float x) {
  float a = fabsf(x) * 0.70710678118654752f;
  float t = __builtin_amdgcn_rcpf(1.0f + 0.3275911f * a);
  float y = t * (0.254829592f +
            t * (-0.284496736f +
            t * (1.421413741f +
            t * (-1.453152027f +
            t * 1.061405429f))));
  float e = __expf(-a * a);
  float erf_abs = 1.0f - y * e;
  float erf_v = (x < 0.f) ? -erf_abs : erf_abs;
  return 0.5f * x * (1.0f + erf_v);
}

// LDS-tile transpose+convert helper: in [z-block pre-offset] [R][C] f32 ->
// out [C][R] bf16, 64x64 tile at (r0, c0). tile = float[64][65] in LDS.
__device__ __forceinline__ void transpose_tile(
    const float* __restrict__ ip, unsigned short* __restrict__ op,
    int R, int C, int r0, int c0, float* tile, int tid) {
  int tx = tid & 63, ty = tid >> 6;
#pragma unroll
  for (int i = 0; i < 16; ++i) {
    int r = i * 4 + ty;
    tile[r * 65 + tx] = ip[(size_t)(r0 + r) * C + c0 + tx];
  }
  __syncthreads();
#pragma unroll
  for (int uu = 0; uu < 4; ++uu) {
    int u = uu * 256 + tid;
    int cc = u >> 4, q = u & 15;
    ushort4 o;
    o.x = f2bf(tile[(q * 4 + 0) * 65 + cc]);
    o.y = f2bf(tile[(q * 4 + 1) * 65 + cc]);
    o.z = f2bf(tile[(q * 4 + 2) * 65 + cc]);
    o.w = f2bf(tile[(q * 4 + 3) * 65 + cc]);
    *(ushort4*)(op + (size_t)(c0 + cc) * R + r0 + q * 4) = o;
  }
}

// ------------- prep: gates | x->bf16 | W1^T->bf16 ----------------------
#define PREP_CONV_BLKS 4096
#define PREP_TR_BLKS   2048
#define PREP_TOTAL     (1 + PREP_CONV_BLKS + PREP_TR_BLKS)

__global__ __launch_bounds__(256) void prep_kernel(
    const float* __restrict__ logits, const int* __restrict__ masks,
    const float* __restrict__ x,
    const float* __restrict__ W1,
    int* __restrict__ sel_e, float* __restrict__ sel_g,
    unsigned short* __restrict__ xb,
    unsigned short* __restrict__ w1t) {
  __shared__ float tile[64 * 65];
  int blk = blockIdx.x;
  int tid = threadIdx.x;

  if (blk == 0) {
    int b = tid;
    if (b >= B_SZ) return;
    float lg[E_SZ], p[E_SZ];
    float mx = -1e30f;
    for (int e = 0; e < E_SZ; ++e) { lg[e] = logits[b * E_SZ + e]; mx = fmaxf(mx, lg[e]); }
    float s = 0.f;
    for (int e = 0; e < E_SZ; ++e) { p[e] = expf(lg[e] - mx); s += p[e]; }
    for (int e = 0; e < E_SZ; ++e) p[e] = (masks[b * E_SZ + e] == 1) ? (p[e] / s) : 0.f;
    int i0 = 0, i1 = 1; float v0 = -1.f, v1 = -1.f;
    for (int e = 0; e < E_SZ; ++e) {
      float v = p[e];
      if (v > v0)      { v1 = v0; i1 = i0; v0 = v; i0 = e; }
      else if (v > v1) { v1 = v;  i1 = e; }
    }
    float den = v0 + v1 + 1e-9f;
    sel_e[2 * b] = i0;  sel_e[2 * b + 1] = i1;
    sel_g[2 * b] = v0 / den;
    sel_g[2 * b + 1] = v1 / den;
    return;
  }
  blk -= 1;

  if (blk < PREP_CONV_BLKS) {
    int i = blk * 256 + tid;
    float4 v = ((const float4*)x)[i];
    ushort4 o;
    o.x = f2bf(v.x); o.y = f2bf(v.y); o.z = f2bf(v.z); o.w = f2bf(v.w);
    ((ushort4*)xb)[i] = o;
    return;
  }
  blk -= PREP_CONV_BLKS;

  // W1 [E][D][F] -> w1t [E][F][D] : R=D=512, C=F=2048, 8x32 tiles (ls=5)
  int z = blk >> 8;
  int rem = blk & 255;
  int tr = rem >> 5, tc = rem & 31;
  transpose_tile(W1 + (size_t)z * D_SZ * F_SZ, w1t + (size_t)z * D_SZ * F_SZ,
                 D_SZ, F_SZ, tr * 64, tc * 64, tile, tid);
}

// ------------- stage 1 + backfilled W2 transpose -----------------------
// blocks [0,2048): H[p] = gelu(X_b @ W1[e] + b1[e]); R3 natural order
//   (f fastest). Both operands staged via global_load_lds, XOR-swizzled
//   k-chunks; 32x32x16 MFMA; two BK=32 sub-tiles per barrier-pair.
// blocks [2048,4096): W2 [E][F][D] -> w2t [E][D][F] transpose (memory-bound
//   backfill under the compute-bound gemm blocks).
__global__ __launch_bounds__(256, 4) void moe_gemm1(
    const unsigned short* __restrict__ Xb,
    const unsigned short* __restrict__ W1t,
    const float* __restrict__ b1,
    const int* __restrict__ sel_e,
    unsigned short* __restrict__ H,
    const float* __restrict__ W2,
    unsigned short* __restrict__ w2t) {
  __shared__ __align__(16) char smem[32768];
  int tid = threadIdx.x;
  int lin = blockIdx.x;

  if (lin >= 2048) {
    // W2 transpose role: R=F=2048, C=D=512, 32x8 tiles (ls=3)
    int blk = lin - 2048;
    int z = blk >> 8;
    int rem = blk & 255;
    int tr = rem >> 3, tc = rem & 7;
    transpose_tile(W2 + (size_t)z * F_SZ * D_SZ, w2t + (size_t)z * F_SZ * D_SZ,
                   F_SZ, D_SZ, tr * 64, tc * 64, (float*)smem, tid);
    return;
  }

  unsigned short* As = (unsigned short*)smem;            // [2][128*BK2]
  unsigned short* Bs = (unsigned short*)(smem + 16384);  // [2][128*BK2]

  int f  = lin & 15;
  int l0 = ((lin >> 4) & 1) * 128;
  int p  = lin >> 5;
  int f0 = f * 128;
  int b  = p >> 1;
  int e  = sel_e[p];

  int lane = tid & 63;
  int w = tid >> 6, wm = w & 1, wn = w >> 1;
  int m32 = lane & 31, kh = lane >> 5;
  int sw = (m32 >> 1) & 3;       // read-side XOR swizzle

  const unsigned short* Abase = Xb  + ((size_t)b * L_SZ + l0) * D_SZ;
  const unsigned short* Bbase = W1t + ((size_t)e * F_SZ + f0) * D_SZ;

  // staging: 512 segs of 16B per sub-tile; seg (row, slot) fetches global
  // k-chunk slot ^ ((row>>1)&3)
  int seg0 = w * 128 + lane;
  int row0 = seg0 >> 2, ks0 = ((seg0 & 3) ^ ((row0 >> 1) & 3)) * 8;
  int seg1 = seg0 + 64;
  int row1 = seg1 >> 2, ks1 = ((seg1 & 3) ^ ((row1 >> 1) & 3)) * 8;

  f32x16 acc[2][2] = {};

  for (int k0 = 0; k0 < D_SZ; k0 += 2 * BK2) {
#pragma unroll
    for (int h = 0; h < 2; ++h) {
      int kk = k0 + h * BK2;
      async16(Abase + (size_t)row0 * D_SZ + kk + ks0, &As[(h * 512 + seg0) * 8]);
      async16(Abase + (size_t)row1 * D_SZ + kk + ks1, &As[(h * 512 + seg1) * 8]);
      async16(Bbase + (size_t)row0 * D_SZ + kk + ks0, &Bs[(h * 512 + seg0) * 8]);
      async16(Bbase + (size_t)row1 * D_SZ + kk + ks1, &Bs[(h * 512 + seg1) * 8]);
    }
    __syncthreads();
#pragma unroll
    for (int h = 0; h < 2; ++h)
#pragma unroll
      for (int s = 0; s < 2; ++s) {     // K=16 substep
        int ko = ((((s << 1) | kh) ^ sw) << 3) + h * 4096;
        bf16x8 a0  = *(const bf16x8*)&As[(wm * 64 +      m32) * BK2 + ko];
        bf16x8 a1  = *(const bf16x8*)&As[(wm * 64 + 32 + m32) * BK2 + ko];
        bf16x8 b0  = *(const bf16x8*)&Bs[(wn * 64 +      m32) * BK2 + ko];
        bf16x8 b1f = *(const bf16x8*)&Bs[(wn * 64 + 32 + m32) * BK2 + ko];
        acc[0][0] = __builtin_amdgcn_mfma_f32_32x32x16_bf16(a0, b0,  acc[0][0], 0, 0, 0);
        acc[0][1] = __builtin_amdgcn_mfma_f32_32x32x16_bf16(a0, b1f, acc[0][1], 0, 0, 0);
        acc[1][0] = __builtin_amdgcn_mfma_f32_32x32x16_bf16(a1, b0,  acc[1][0], 0, 0, 0);
        acc[1][1] = __builtin_amdgcn_mfma_f32_32x32x16_bf16(a1, b1f, acc[1][1], 0, 0, 0);
      }
    __syncthreads();
  }

  // epilogue: +b1, gelu, bf16 direct stores (32 lanes -> 64B contiguous)
  float b1v[2];
#pragma unroll
  for (int tj = 0; tj < 2; ++tj)
    b1v[tj] = b1[e * F_SZ + f0 + wn * 64 + tj * 32 + m32];

  unsigned short* Hp = H + ((size_t)p * L_SZ + l0) * F_SZ + f0;
#pragma unroll
  for (int ti = 0; ti < 2; ++ti)
#pragma unroll
    for (int tj = 0; tj < 2; ++tj) {
      int col = wn * 64 + tj * 32 + m32;
#pragma unroll
      for (int r = 0; r < 16; ++r) {
        int row = wm * 64 + ti * 32 + (r & 3) + 8 * (r >> 2) + 4 * kh;
        Hp[(size_t)row * F_SZ + col] = f2bf(gelu_f(acc[ti][tj][r] + b1v[tj]));
      }
    }
}

// ------------- stage 2 (slot-split, full K, no atomics) ----------------
// even slot p -> part = g0*acc ; odd slot p -> Out = g1*acc + gate-wtd b2
__global__ __launch_bounds__(256, 4) void moe_gemm2(
    const unsigned short* __restrict__ H,
    const unsigned short* __restrict__ W2t,
    const float* __restrict__ b2,
    const int* __restrict__ sel_e,
    const float* __restrict__ sel_g,
    float* __restrict__ part,
    float* __restrict__ Out) {
  __shared__ __align__(16) unsigned short As[2][128 * BK2];
  __shared__ __align__(16) unsigned short Bs[2][128 * BK2];

  int lin = blockIdx.x;
  int q   = lin & 7;
  int d   = (lin >> 3) & 3;
  int g8  = lin >> 5;
  int gg  = g8 * 8 + q;          // (p, l-tile), 0..127 — same XCD across d
  int p   = gg >> 1;
  int l0  = (gg & 1) * 128;
  int d0  = d * 128;
  int b   = p >> 1;
  int e   = sel_e[p];
  float g = sel_g[p];

  int tid = threadIdx.x;
  int lane = tid & 63;
  int w = tid >> 6, wm = w & 1, wn = w >> 1;
  int m32 = lane & 31, kh = lane >> 5;
  int sw = (m32 >> 1) & 3;

  const unsigned short* Abase = H   + ((size_t)p * L_SZ + l0) * F_SZ;
  const unsigned short* Bbase = W2t + ((size_t)e * D_SZ + d0) * F_SZ;

  int seg0 = w * 128 + lane;
  int row0 = seg0 >> 2, ks0 = ((seg0 & 3) ^ ((row0 >> 1) & 3)) * 8;
  int seg1 = seg0 + 64;
  int row1 = seg1 >> 2, ks1 = ((seg1 & 3) ^ ((row1 >> 1) & 3)) * 8;

  f32x16 acc[2][2] = {};

  for (int k0 = 0; k0 < F_SZ; k0 += 2 * BK2) {
#pragma unroll
    for (int h = 0; h < 2; ++h) {
      int kk = k0 + h * BK2;
      async16(Abase + (size_t)row0 * F_SZ + kk + ks0, &As[h][seg0 * 8]);
      async16(Abase + (size_t)row1 * F_SZ + kk + ks1, &As[h][seg1 * 8]);
      async16(Bbase + (size_t)row0 * F_SZ + kk + ks0, &Bs[h][seg0 * 8]);
      async16(Bbase + (size_t)row1 * F_SZ + kk + ks1, &Bs[h][seg1 * 8]);
    }
    __syncthreads();
#pragma unroll
    for (int h = 0; h < 2; ++h)
#pragma unroll
      for (int s = 0; s < 2; ++s) {
        int ko = (((s << 1) | kh) ^ sw) << 3;
        bf16x8 a0  = *(const bf16x8*)&As[h][(wm * 64 +      m32) * BK2 + ko];
        bf16x8 a1  = *(const bf16x8*)&As[h][(wm * 64 + 32 + m32) * BK2 + ko];
        bf16x8 b0  = *(const bf16x8*)&Bs[h][(wn * 64 +      m32) * BK2 + ko];
        bf16x8 b1f = *(const bf16x8*)&Bs[h][(wn * 64 + 32 + m32) * BK2 + ko];
        acc[0][0] = __builtin_amdgcn_mfma_f32_32x32x16_bf16(a0, b0,  acc[0][0], 0, 0, 0);
        acc[0][1] = __builtin_amdgcn_mfma_f32_32x32x16_bf16(a0, b1f, acc[0][1], 0, 0, 0);
        acc[1][0] = __builtin_amdgcn_mfma_f32_32x32x16_bf16(a1, b0,  acc[1][0], 0, 0, 0);
        acc[1][1] = __builtin_amdgcn_mfma_f32_32x32x16_bf16(a1, b1f, acc[1][1], 0, 0, 0);
      }
    __syncthreads();
  }

  // epilogue: gate-scale (+ gate-weighted b2 on odd slot), direct f32 stores
  float bias[2] = {0.f, 0.f};
  if (p & 1) {
    int e0 = sel_e[2 * b], e1 = sel_e[2 * b + 1];
    float g0 = sel_g[2 * b], g1 = sel_g[2 * b + 1];
#pragma unroll
    for (int tj = 0; tj < 2; ++tj) {
      int dd = d0 + wn * 64 + tj * 32 + m32;
      bias[tj] = g0 * b2[e0 * D_SZ + dd] + g1 * b2[e1 * D_SZ + dd];
    }
  }
  float* dst = (p & 1) ? Out : part;
  float* Op = dst + ((size_t)b * L_SZ + l0) * D_SZ + d0;
#pragma unroll
  for (int ti = 0; ti < 2; ++ti)
#pragma unroll
    for (int tj = 0; tj < 2; ++tj) {
      int col = wn * 64 + tj * 32 + m32;
#pragma unroll
      for (int r = 0; r < 16; ++r) {
        int row = wm * 64 + ti * 32 + (r & 3) + 8 * (r >> 2) + 4 * kh;
        Op[(size_t)row * D_SZ + col] = g * acc[ti][tj][r] + bias[tj];
      }
    }
}

// ------------- combine: Out += part ------------------------------------
__global__ __launch_bounds__(256) void combine_kernel(
    const float* __restrict__ part, float* __restrict__ Out) {
  int i = blockIdx.x * 256 + threadIdx.x;
  float4 pv = ((const float4*)part)[i];
  float4 o  = ((float4*)Out)[i];
  o.x += pv.x; o.y += pv.y; o.z += pv.z; o.w += pv.w;
  ((float4*)Out)[i] = o;
}

extern "C" void kernel_launch(void* const* d_in, const int* in_sizes, int n_in,
                              void* d_out, int out_size, void* d_ws, size_t ws_size,
                              hipStream_t stream) {
  const float* x      = (const float*)d_in[0];
  const float* logits = (const float*)d_in[1];
  const int*   masks  = (const int*)d_in[2];
  const float* W1     = (const float*)d_in[3];
  const float* b1     = (const float*)d_in[4];
  const float* W2     = (const float*)d_in[5];
  const float* b2     = (const float*)d_in[6];
  float* out = (float*)d_out;

  // workspace: sel (1K) | xb 8MB | w1t 16MB | w2t 16MB | H 64MB
  // part (16MB f32) aliases [xb .. first half of w1t] — dead after gemm1.
  char* ws = (char*)d_ws;
  int*   sel_e = (int*)ws;
  float* sel_g = (float*)(ws + 256);
  unsigned short* xb  = (unsigned short*)(ws + 1024);
  unsigned short* w1t = xb  + (size_t)B_SZ * L_SZ * D_SZ;
  unsigned short* w2t = w1t + (size_t)E_SZ * F_SZ * D_SZ;
  unsigned short* Hbuf = w2t + (size_t)E_SZ * D_SZ * F_SZ;
  float* part = (float*)(ws + 1024);

  prep_kernel<<<PREP_TOTAL, 256, 0, stream>>>(logits, masks, x, W1,
                                              sel_e, sel_g, xb, w1t);
  moe_gemm1<<<4096, 256, 0, stream>>>(xb, w1t, b1, sel_e, Hbuf, W2, w2t);
  moe_gemm2<<<512, 256, 0, stream>>>(Hbuf, w2t, b2, sel_e, sel_g, part, out);
  combine_kernel<<<(B_SZ * L_SZ * D_SZ / 4) / 256, 256, 0, stream>>>(part, out);
}